// Round 14
// baseline (7923.408 us; speedup 1.0000x reference)
//
#include <hip/hip_runtime.h>
#include <stdint.h>

// VanillaRNN: B=128, T=512, I=128, H=2048, O=10
// R14: R8 (proven 2141us) + XCD-L2-shared h reads:
//   - h loads are PLAIN cached loads (no sc1);
//   - after its producer-flag poll, each wave issues an acquire-agent fence
//     (flash L1+L2 invalidate; caches are clean since h stores write through)
//     so post-fence loads refill from MALL and the 4 WGs of a row-group on
//     each XCD share one L2 fill (16MB -> ~4MB MALL traffic per step).
//   - tanh via __expf (shorter reducer critical path).
//   Everything else (flag protocol, stores, barriers, epilogue) = R8.

#define B_   128
#define T_   512
#define I_   128
#define H_   2048
#define O_   10
#define KK   2176
#define NWG  256
#define NTHR 512

typedef __attribute__((ext_vector_type(8))) _Float16 f16x8;
typedef __attribute__((ext_vector_type(4))) float    f32x4;
typedef __attribute__((ext_vector_type(4))) int      i32x4;

__device__ __forceinline__ float f16_to_f(unsigned short u) {
    return (float)__builtin_bit_cast(_Float16, u);
}
__device__ __forceinline__ unsigned short f_to_f16(float f) {
    return __builtin_bit_cast(unsigned short, (_Float16)f);
}

// system-scope coherent 8B store (write-through; proven visibility)
__device__ __forceinline__ void st64cc(unsigned short* p, uint64_t v) {
    asm volatile("global_store_dwordx2 %0, %1, off sc0 sc1"
                 :: "v"((uint64_t)(uintptr_t)p), "v"(v) : "memory");
}
// flag ops: system scope (proven protocol)
__device__ __forceinline__ void stflag(unsigned int* p, uint32_t v) {
    asm volatile("global_store_dword %0, %1, off sc0 sc1"
                 :: "v"((uint64_t)(uintptr_t)p), "v"(v) : "memory");
}
__device__ __forceinline__ uint32_t ldflag(const unsigned int* p) {
    uint32_t v;
    asm volatile("global_load_dword %0, %1, off sc0 sc1"
                 : "=v"(v) : "v"((uint64_t)(uintptr_t)p) : "memory");
    asm volatile("s_waitcnt vmcnt(0)" ::: "memory");
    __builtin_amdgcn_sched_barrier(0);
    return v;
}

#define MFMA16(a, b, c) __builtin_amdgcn_mfma_f32_16x16x32_f16((a), (b), (c), 0, 0, 0)

__global__ void prep_init(unsigned int* flags) {
    for (int i = threadIdx.x; i < 8192; i += blockDim.x) flags[i] = 0u;
}

// Transpose + f16 convert: Wt[n][k]; k<2048 -> W_hh, k>=2048 -> W_hx.
__global__ void prep_weights(const float* __restrict__ Whh, const float* __restrict__ Whx,
                             unsigned short* __restrict__ Wt) {
    __shared__ float tile[32][33];
    const int kt = blockIdx.x;
    const int nt = blockIdx.y;
    const int tx = threadIdx.x & 31;
    const int ty = threadIdx.x >> 5;
#pragma unroll
    for (int r = ty; r < 32; r += 8) {
        const int k = kt * 32 + r;
        const int n = nt * 32 + tx;
        tile[r][tx] = (k < H_) ? Whh[(size_t)k * H_ + n] : Whx[(size_t)(k - H_) * H_ + n];
    }
    __syncthreads();
#pragma unroll
    for (int r = ty; r < 32; r += 8) {
        const int n = nt * 32 + r;
        const int k = kt * 32 + tx;
        Wt[(size_t)n * KK + k] = f_to_f16(tile[tx][r]);
    }
}

__global__ __launch_bounds__(NTHR, 2) void rnn_scan(
    const float* __restrict__ x,              // [B][T][I] f32
    const unsigned short* __restrict__ Wt,    // [H][KK] f16
    const float* __restrict__ b_h,
    const float* __restrict__ W_ph,           // [H][O]
    const float* __restrict__ b_o,
    unsigned short* __restrict__ h0,          // [B][H] f16 ping
    unsigned short* __restrict__ h1,          // [B][H] f16 pong
    float* __restrict__ out,                  // [B][O]
    unsigned int* __restrict__ flags)
{
    const int tid  = threadIdx.x;
    const int wg   = blockIdx.x;
    const int w    = tid >> 6;        // wave 0..7 = k-eighth
    const int lane = tid & 63;
    const int l15  = lane & 15;
    const int l4   = lane >> 4;
    const int rb   = wg >> 5;         // row-group 0..7 (rows rb*16..+16)
    const int cb   = wg & 31;         // col block 0..31
    const int r0   = rb * 16;
    const int c0   = cb * 64;
    const int arow = r0 + l15;

    unsigned int* gslots = flags + 16 + (size_t)(rb * 32) * 16;  // group's 32 slots
    unsigned int* myslot = gslots + (size_t)cb * 16;
    // wave w's 4 producers: peers cb' = 4w .. 4w+3 (cols [cb'*64,+64))
    unsigned int* prodslot = gslots + (size_t)((w * 4 + (lane & 3)) * 16);

    __shared__ f32x4 red[8][4][64];          // [wave][ntile][lane] 32 KB
    __shared__ unsigned short hT[16][68];    // h tile staging (padded)
    __shared__ float epi[128];
    __shared__ float lgt[16];

    // ---- W panel into registers (f16, const over t) ----
    i32x4 wh[4][8];
    i32x4 wx[4];
#pragma unroll
    for (int n = 0; n < 4; ++n) {
        const size_t colbase = (size_t)(c0 + n * 16 + l15) * KK;
#pragma unroll
        for (int j = 0; j < 8; ++j)
            wh[n][j] = *(const i32x4*)(Wt + colbase + (size_t)(w * 256 + j * 32 + l4 * 8));
        if (w >= 4)
            wx[n] = *(const i32x4*)(Wt + colbase + (size_t)(2048 + (w - 4) * 32 + l4 * 8));
    }

    // reducer constants (tid < 256)
    const int rn   = tid >> 6;
    const int rL   = tid & 63;
    const int lcol = rn * 16 + (rL & 15);    // local col 0..63
    const int lr0  = (rL >> 4) * 4;          // local row 0,4,8,12
    const float rbias = b_h[c0 + lcol];
    const int slr = tid >> 4;                // store: local row 0..15
    const int scg = tid & 15;                // store: col group 0..15

    for (int t = 0; t < T_; ++t) {
        const unsigned short* rh  = (t & 1) ? h0 : h1;   // read buf (h_t)
        unsigned short*       whp = (t & 1) ? h1 : h0;   // write buf (h_{t+1})

        f32x4 acc[4];
#pragma unroll
        for (int n = 0; n < 4; ++n) acc[n] = f32x4{0.f, 0.f, 0.f, 0.f};

        // ---- x contribution FIRST (waves 4..7; independent of peers) ----
        if (w >= 4) {
            const float* xp = x + ((size_t)arow * T_ + t) * I_ + (size_t)((w - 4) * 32 + l4 * 8);
            const f32x4 xa = *(const f32x4*)xp;
            const f32x4 xb = *(const f32x4*)(xp + 4);
            f16x8 xv;
#pragma unroll
            for (int jj = 0; jj < 8; ++jj)
                xv[jj] = (_Float16)((jj < 4) ? xa[jj] : xb[jj - 4]);
#pragma unroll
            for (int n = 0; n < 4; ++n)
                acc[n] = MFMA16(xv, __builtin_bit_cast(f16x8, wx[n]), acc[n]);
        }

        if (t > 0) {
            // ---- per-wave producer poll (R8) ----
            for (;;) {
                uint32_t v = 0xFFFFFFFFu;
                if ((lane & ~3) == 0) v = ldflag(prodslot);   // lanes 0..3
                if (__all((int)(v >= (unsigned)t))) break;
            }

            // ---- invalidate stale L1/L2 lines, then CACHED h loads ----
            __builtin_amdgcn_fence(__ATOMIC_ACQUIRE, "agent");

            const uint64_t base64 = (uint64_t)(uintptr_t)(rh + (size_t)arow * H_ + (size_t)(w * 256 + l4 * 8));
            i32x4 hb[8];
#define ISSJ(jj, IMM) \
    asm volatile("global_load_dwordx4 %0, %1, off offset:" IMM \
                 : "=v"(hb[jj]) : "v"(base64) : "memory")
#define WAITV(NSTR) do { \
    asm volatile("s_waitcnt vmcnt(" NSTR ")" ::: "memory"); \
    __builtin_amdgcn_sched_barrier(0); } while (0)
#define CONS(jj) do { \
    const f16x8 AH = __builtin_bit_cast(f16x8, hb[jj]); \
    acc[0] = MFMA16(AH, __builtin_bit_cast(f16x8, wh[0][jj]), acc[0]); \
    acc[1] = MFMA16(AH, __builtin_bit_cast(f16x8, wh[1][jj]), acc[1]); \
    acc[2] = MFMA16(AH, __builtin_bit_cast(f16x8, wh[2][jj]), acc[2]); \
    acc[3] = MFMA16(AH, __builtin_bit_cast(f16x8, wh[3][jj]), acc[3]); \
    } while (0)
            ISSJ(0, "0");   ISSJ(1, "64");  ISSJ(2, "128"); ISSJ(3, "192");
            ISSJ(4, "256"); ISSJ(5, "320"); ISSJ(6, "384"); ISSJ(7, "448");
            WAITV("7"); CONS(0);
            WAITV("6"); CONS(1);
            WAITV("5"); CONS(2);
            WAITV("4"); CONS(3);
            WAITV("3"); CONS(4);
            WAITV("2"); CONS(5);
            WAITV("1"); CONS(6);
            WAITV("0"); CONS(7);
#undef ISSJ
#undef WAITV
#undef CONS
        }

        // ---- cross-wave k-reduce via LDS ----
#pragma unroll
        for (int n = 0; n < 4; ++n) red[w][n][lane] = acc[n];
        __syncthreads();

        if (tid < 256) {
            f32x4 v = red[0][rn][rL];
#pragma unroll
            for (int p = 1; p < 8; ++p) v += red[p][rn][rL];
#pragma unroll
            for (int r = 0; r < 4; ++r) {
                const float pre = v[r] + rbias;
                const float e   = __expf(2.f * pre);
                const float hv  = 1.f - 2.f / (e + 1.f);
                hT[lr0 + r][lcol] = f_to_f16(hv);
            }
        }
        __syncthreads();

        // ---- coalesced h store: 8B contiguous per thread (R8) ----
        if (tid < 256) {
            const uint64_t val = *(const uint64_t*)&hT[slr][scg * 4];
            st64cc(whp + (size_t)(r0 + slr) * H_ + (size_t)(c0 + scg * 4), val);
        }
        asm volatile("s_waitcnt vmcnt(0)" ::: "memory");   // own stores acked
        __syncthreads();                                    // all waves drained

        if (tid == 0) stflag(myslot, (unsigned)(t + 1));
    }

    // ---- final group sync: all peers' h_T visible ----
    if (w == 0) {
        for (;;) {
            uint32_t v = 0xFFFFFFFFu;
            if (lane < 32) v = ldflag(gslots + (size_t)lane * 16);
            if (__all((int)(v >= (unsigned)T_))) break;
        }
    }
    __syncthreads();

    // ---- epilogue: row r0+cb handled by OWNER group rb (cb<16); h_T in h1 ----
    if (cb < 16) {
        const int b = r0 + cb;
        float o[O_];
#pragma unroll
        for (int j = 0; j < O_; ++j) o[j] = 0.f;
        const uint64_t hbase = (uint64_t)(uintptr_t)(h1 + (size_t)b * H_ + (size_t)tid * 4);
        uint64_t hh;
        asm volatile("global_load_dwordx2 %0, %1, off sc1"
                     : "=v"(hh) : "v"(hbase) : "memory");
        asm volatile("s_waitcnt vmcnt(0)" ::: "memory");
        __builtin_amdgcn_sched_barrier(0);
#pragma unroll
        for (int e = 0; e < 4; ++e) {
            const float hv = f16_to_f((unsigned short)(hh >> (16 * e)));
            const float* wrow = W_ph + (size_t)(tid * 4 + e) * O_;
#pragma unroll
            for (int j = 0; j < O_; ++j) o[j] += hv * wrow[j];
        }
#pragma unroll
        for (int off = 32; off > 0; off >>= 1) {
#pragma unroll
            for (int j = 0; j < O_; ++j) o[j] += __shfl_down(o[j], off);
        }
        if (lane == 0) {
#pragma unroll
            for (int j = 0; j < O_; ++j) epi[w * 16 + j] = o[j];
        }
        __syncthreads();
        if (tid < O_) {
            float l = b_o[tid];
#pragma unroll
            for (int ww = 0; ww < 8; ++ww) l += epi[ww * 16 + tid];
            lgt[tid] = l;
        }
        __syncthreads();
        if (tid < O_) {
            float m = lgt[0];
#pragma unroll
            for (int j = 1; j < O_; ++j) m = fmaxf(m, lgt[j]);
            float ssum = 0.f;
#pragma unroll
            for (int j = 0; j < O_; ++j) ssum += expf(lgt[j] - m);
            out[(size_t)b * O_ + tid] = expf(lgt[tid] - m) / ssum;
        }
    }
}

extern "C" void kernel_launch(void* const* d_in, const int* in_sizes, int n_in,
                              void* d_out, int out_size, void* d_ws, size_t ws_size,
                              hipStream_t stream) {
    const float* x    = (const float*)d_in[0];
    const float* Whx  = (const float*)d_in[1];
    const float* Whh  = (const float*)d_in[2];
    const float* bh   = (const float*)d_in[3];
    const float* Wph  = (const float*)d_in[4];
    const float* bo   = (const float*)d_in[5];
    float* out = (float*)d_out;

    // ws: flags 32KB | Wt (f16, 8.9MB) | h ping-pong (f16, 512KB x2)
    char* ws = (char*)d_ws;
    unsigned int*   flags = (unsigned int*)ws;
    unsigned short* Wt    = (unsigned short*)(ws + 32768);
    unsigned short* h0    = Wt + (size_t)H_ * KK;
    unsigned short* h1    = h0 + (size_t)B_ * H_;

    hipLaunchKernelGGL(prep_init, dim3(1), dim3(256), 0, stream, flags);
    hipLaunchKernelGGL(prep_weights, dim3(68, 64), dim3(256), 0, stream, Whh, Whx, Wt);

    void* args[] = {
        (void*)&x, (void*)&Wt, (void*)&bh, (void*)&Wph, (void*)&bo,
        (void*)&h0, (void*)&h1, (void*)&out, (void*)&flags
    };
    hipLaunchCooperativeKernel((const void*)rnn_scan, dim3(NWG), dim3(NTHR), args, 0, stream);
}

// Round 16
// 2134.921 us; speedup vs baseline: 3.7113x; 3.7113x over previous
//
#include <hip/hip_runtime.h>
#include <stdint.h>

// VanillaRNN: B=128, T=512, I=128, H=2048, O=10
// R16: R8 protocol with single-barrier producer tail + per-wave sub-flags.
//   - red[] parity-double-buffered (R11-proven) -> ONE __syncthreads/step.
//   - reducer waves 0-3: reduce -> tanh -> 4x scattered 2B sc0sc1 stores
//     (R6-proven) -> own-wave vmcnt(0) -> own sub-flag. No hT staging, no
//     block-wide drain; waves 4-7 run ahead to t+1.
//   - consumers poll 16 sub-slots (4 producer WGs x 4 reducer waves).
//   W f16 in registers; h f16 ping-pong; everything else R8.

#define B_   128
#define T_   512
#define I_   128
#define H_   2048
#define O_   10
#define KK   2176
#define NWG  256
#define NTHR 512

typedef __attribute__((ext_vector_type(8))) _Float16 f16x8;
typedef __attribute__((ext_vector_type(4))) float    f32x4;
typedef __attribute__((ext_vector_type(4))) int      i32x4;

__device__ __forceinline__ float f16_to_f(unsigned short u) {
    return (float)__builtin_bit_cast(_Float16, u);
}
__device__ __forceinline__ unsigned short f_to_f16(float f) {
    return __builtin_bit_cast(unsigned short, (_Float16)f);
}

// system-scope coherent stores (proven visibility)
__device__ __forceinline__ void st16cc(unsigned short* p, unsigned short v) {
    asm volatile("global_store_short %0, %1, off sc0 sc1"
                 :: "v"((uint64_t)(uintptr_t)p), "v"((uint32_t)v) : "memory");
}
__device__ __forceinline__ void stflag(unsigned int* p, uint32_t v) {
    asm volatile("global_store_dword %0, %1, off sc0 sc1"
                 :: "v"((uint64_t)(uintptr_t)p), "v"(v) : "memory");
}
__device__ __forceinline__ uint32_t ldflag(const unsigned int* p) {
    uint32_t v;
    asm volatile("global_load_dword %0, %1, off sc0 sc1"
                 : "=v"(v) : "v"((uint64_t)(uintptr_t)p) : "memory");
    asm volatile("s_waitcnt vmcnt(0)" ::: "memory");
    __builtin_amdgcn_sched_barrier(0);
    return v;
}

#define MFMA16(a, b, c) __builtin_amdgcn_mfma_f32_16x16x32_f16((a), (b), (c), 0, 0, 0)

__global__ void prep_init(unsigned int* flags) {
    for (int i = threadIdx.x; i < 24576; i += blockDim.x) flags[i] = 0u;
}

// Transpose + f16 convert: Wt[n][k]; k<2048 -> W_hh, k>=2048 -> W_hx.
__global__ void prep_weights(const float* __restrict__ Whh, const float* __restrict__ Whx,
                             unsigned short* __restrict__ Wt) {
    __shared__ float tile[32][33];
    const int kt = blockIdx.x;
    const int nt = blockIdx.y;
    const int tx = threadIdx.x & 31;
    const int ty = threadIdx.x >> 5;
#pragma unroll
    for (int r = ty; r < 32; r += 8) {
        const int k = kt * 32 + r;
        const int n = nt * 32 + tx;
        tile[r][tx] = (k < H_) ? Whh[(size_t)k * H_ + n] : Whx[(size_t)(k - H_) * H_ + n];
    }
    __syncthreads();
#pragma unroll
    for (int r = ty; r < 32; r += 8) {
        const int n = nt * 32 + r;
        const int k = kt * 32 + tx;
        Wt[(size_t)n * KK + k] = f_to_f16(tile[tx][r]);
    }
}

__global__ __launch_bounds__(NTHR, 2) void rnn_scan(
    const float* __restrict__ x,              // [B][T][I] f32
    const unsigned short* __restrict__ Wt,    // [H][KK] f16
    const float* __restrict__ b_h,
    const float* __restrict__ W_ph,           // [H][O]
    const float* __restrict__ b_o,
    unsigned short* __restrict__ h0,          // [B][H] f16 ping
    unsigned short* __restrict__ h1,          // [B][H] f16 pong
    float* __restrict__ out,                  // [B][O]
    unsigned int* __restrict__ flags)
{
    const int tid  = threadIdx.x;
    const int wg   = blockIdx.x;
    const int w    = tid >> 6;        // wave 0..7 = k-eighth
    const int lane = tid & 63;
    const int l15  = lane & 15;
    const int l4   = lane >> 4;
    const int rb   = wg >> 5;         // row-group 0..7 (rows rb*16..+16)
    const int cb   = wg & 31;         // col block 0..31
    const int r0   = rb * 16;
    const int c0   = cb * 64;
    const int arow = r0 + l15;

    // sub-flag layout: flags + 16 + ((rb*32 + cb)*4 + wave)*16  (64B/slot)
    unsigned int* gslots = flags + 16 + (size_t)(rb * 32) * 64;
    unsigned int* mysub  = gslots + (size_t)cb * 64 + (size_t)w * 16;          // w<4
    unsigned int* pollsl = gslots + (size_t)(w * 4 + (lane >> 2)) * 64
                                  + (size_t)(lane & 3) * 16;                   // lane<16

    __shared__ f32x4 red[2][8][4][64];       // parity-double-buffered (64 KB)
    __shared__ float epi[128];
    __shared__ float lgt[16];

    // ---- W panel into registers (f16, const over t) ----
    i32x4 wh[4][8];
    i32x4 wx[4];
#pragma unroll
    for (int n = 0; n < 4; ++n) {
        const size_t colbase = (size_t)(c0 + n * 16 + l15) * KK;
#pragma unroll
        for (int j = 0; j < 8; ++j)
            wh[n][j] = *(const i32x4*)(Wt + colbase + (size_t)(w * 256 + j * 32 + l4 * 8));
        if (w >= 4)
            wx[n] = *(const i32x4*)(Wt + colbase + (size_t)(2048 + (w - 4) * 32 + l4 * 8));
    }

    // reducer constants (tid < 256): wave w reduces ntile w
    const int rn    = tid >> 6;              // = w for tid<256
    const int rL    = tid & 63;
    const int rcol  = c0 + rn * 16 + (rL & 15);
    const int rrow0 = r0 + (rL >> 4) * 4;
    const float rbias = b_h[rcol];

    for (int t = 0; t < T_; ++t) {
        const int par = t & 1;
        const unsigned short* rh  = (t & 1) ? h0 : h1;   // read buf (h_t)
        unsigned short*       whp = (t & 1) ? h1 : h0;   // write buf (h_{t+1})

        f32x4 acc[4];
#pragma unroll
        for (int n = 0; n < 4; ++n) acc[n] = f32x4{0.f, 0.f, 0.f, 0.f};

        // ---- x contribution FIRST (waves 4..7; independent of peers) ----
        if (w >= 4) {
            const float* xp = x + ((size_t)arow * T_ + t) * I_ + (size_t)((w - 4) * 32 + l4 * 8);
            const f32x4 xa = *(const f32x4*)xp;
            const f32x4 xb = *(const f32x4*)(xp + 4);
            f16x8 xv;
#pragma unroll
            for (int jj = 0; jj < 8; ++jj)
                xv[jj] = (_Float16)((jj < 4) ? xa[jj] : xb[jj - 4]);
#pragma unroll
            for (int n = 0; n < 4; ++n)
                acc[n] = MFMA16(xv, __builtin_bit_cast(f16x8, wx[n]), acc[n]);
        }

        if (t > 0) {
            // ---- per-wave producer poll: 4 producer WGs x 4 sub-flags ----
            for (;;) {
                uint32_t v = 0xFFFFFFFFu;
                if (lane < 16) v = ldflag(pollsl);
                if (__all((int)(v >= (unsigned)t))) break;
            }

            // ---- h burst loads + counted drain (R8) ----
            const uint64_t base64 = (uint64_t)(uintptr_t)(rh + (size_t)arow * H_ + (size_t)(w * 256 + l4 * 8));
            i32x4 hb[8];
#define ISSJ(jj, IMM) \
    asm volatile("global_load_dwordx4 %0, %1, off offset:" IMM " sc1" \
                 : "=v"(hb[jj]) : "v"(base64) : "memory")
#define WAITV(NSTR) do { \
    asm volatile("s_waitcnt vmcnt(" NSTR ")" ::: "memory"); \
    __builtin_amdgcn_sched_barrier(0); } while (0)
#define CONS(jj) do { \
    const f16x8 AH = __builtin_bit_cast(f16x8, hb[jj]); \
    acc[0] = MFMA16(AH, __builtin_bit_cast(f16x8, wh[0][jj]), acc[0]); \
    acc[1] = MFMA16(AH, __builtin_bit_cast(f16x8, wh[1][jj]), acc[1]); \
    acc[2] = MFMA16(AH, __builtin_bit_cast(f16x8, wh[2][jj]), acc[2]); \
    acc[3] = MFMA16(AH, __builtin_bit_cast(f16x8, wh[3][jj]), acc[3]); \
    } while (0)
            ISSJ(0, "0");   ISSJ(1, "64");  ISSJ(2, "128"); ISSJ(3, "192");
            ISSJ(4, "256"); ISSJ(5, "320"); ISSJ(6, "384"); ISSJ(7, "448");
            WAITV("7"); CONS(0);
            WAITV("6"); CONS(1);
            WAITV("5"); CONS(2);
            WAITV("4"); CONS(3);
            WAITV("3"); CONS(4);
            WAITV("2"); CONS(5);
            WAITV("1"); CONS(6);
            WAITV("0"); CONS(7);
#undef ISSJ
#undef WAITV
#undef CONS
        }

        // ---- cross-wave k-reduce: parity buffer, ONE barrier ----
#pragma unroll
        for (int n = 0; n < 4; ++n) red[par][w][n][lane] = acc[n];
        __syncthreads();

        // ---- reducer waves: reduce -> tanh -> scattered stores -> own flag ----
        if (tid < 256) {
            f32x4 v = red[par][0][rn][rL];
#pragma unroll
            for (int p = 1; p < 8; ++p) v += red[par][p][rn][rL];
#pragma unroll
            for (int r = 0; r < 4; ++r) {
                const float pre = v[r] + rbias;
                const float e   = __expf(2.f * pre);
                const float hv  = 1.f - 2.f / (e + 1.f);
                st16cc(whp + (size_t)(rrow0 + r) * H_ + rcol, f_to_f16(hv));
            }
            asm volatile("s_waitcnt vmcnt(0)" ::: "memory");   // own stores acked
            if (lane == 0) stflag(mysub, (unsigned)(t + 1));
        }
        // waves 4..7 fall through to t+1 immediately
    }

    // ---- final sync: all 32 peers x 4 sub-flags >= T_ ----
    if (tid < 128) {
        unsigned int* s = gslots + (size_t)(tid >> 2) * 64 + (size_t)(tid & 3) * 16;
        while (ldflag(s) < (unsigned)T_) __builtin_amdgcn_s_sleep(1);
    }
    __syncthreads();

    // ---- epilogue: row r0+cb handled by OWNER group rb (cb<16); h_T in h1 ----
    if (cb < 16) {
        const int b = r0 + cb;
        float o[O_];
#pragma unroll
        for (int j = 0; j < O_; ++j) o[j] = 0.f;
        const uint64_t hbase = (uint64_t)(uintptr_t)(h1 + (size_t)b * H_ + (size_t)tid * 4);
        uint64_t hh;
        asm volatile("global_load_dwordx2 %0, %1, off sc1"
                     : "=v"(hh) : "v"(hbase) : "memory");
        asm volatile("s_waitcnt vmcnt(0)" ::: "memory");
        __builtin_amdgcn_sched_barrier(0);
#pragma unroll
        for (int e = 0; e < 4; ++e) {
            const float hv = f16_to_f((unsigned short)(hh >> (16 * e)));
            const float* wrow = W_ph + (size_t)(tid * 4 + e) * O_;
#pragma unroll
            for (int j = 0; j < O_; ++j) o[j] += hv * wrow[j];
        }
#pragma unroll
        for (int off = 32; off > 0; off >>= 1) {
#pragma unroll
            for (int j = 0; j < O_; ++j) o[j] += __shfl_down(o[j], off);
        }
        if (lane == 0) {
#pragma unroll
            for (int j = 0; j < O_; ++j) epi[w * 16 + j] = o[j];
        }
        __syncthreads();
        if (tid < O_) {
            float l = b_o[tid];
#pragma unroll
            for (int ww = 0; ww < 8; ++ww) l += epi[ww * 16 + tid];
            lgt[tid] = l;
        }
        __syncthreads();
        if (tid < O_) {
            float m = lgt[0];
#pragma unroll
            for (int j = 1; j < O_; ++j) m = fmaxf(m, lgt[j]);
            float ssum = 0.f;
#pragma unroll
            for (int j = 0; j < O_; ++j) ssum += expf(lgt[j] - m);
            out[(size_t)b * O_ + tid] = expf(lgt[tid] - m) / ssum;
        }
    }
}

extern "C" void kernel_launch(void* const* d_in, const int* in_sizes, int n_in,
                              void* d_out, int out_size, void* d_ws, size_t ws_size,
                              hipStream_t stream) {
    const float* x    = (const float*)d_in[0];
    const float* Whx  = (const float*)d_in[1];
    const float* Whh  = (const float*)d_in[2];
    const float* bh   = (const float*)d_in[3];
    const float* Wph  = (const float*)d_in[4];
    const float* bo   = (const float*)d_in[5];
    float* out = (float*)d_out;

    // ws: flags 128KB | Wt (f16, 8.9MB) | h ping-pong (f16, 512KB x2)
    char* ws = (char*)d_ws;
    unsigned int*   flags = (unsigned int*)ws;
    unsigned short* Wt    = (unsigned short*)(ws + 131072);
    unsigned short* h0    = Wt + (size_t)H_ * KK;
    unsigned short* h1    = h0 + (size_t)B_ * H_;

    hipLaunchKernelGGL(prep_init, dim3(1), dim3(256), 0, stream, flags);
    hipLaunchKernelGGL(prep_weights, dim3(68, 64), dim3(256), 0, stream, Whh, Whx, Wt);

    void* args[] = {
        (void*)&x, (void*)&Wt, (void*)&bh, (void*)&Wph, (void*)&bo,
        (void*)&h0, (void*)&h1, (void*)&out, (void*)&flags
    };
    hipLaunchCooperativeKernel((const void*)rnn_scan, dim3(NWG), dim3(NTHR), args, 0, stream);
}